// Round 5
// baseline (1726.312 us; speedup 1.0000x reference)
//
#include <hip/hip_runtime.h>

// Problem constants
#define B_  4096
#define T_  64
#define D_  256
#define E_  128
#define H_  256
#define KS_ 384    // E + H

typedef __attribute__((ext_vector_type(8))) short short8;
typedef __attribute__((ext_vector_type(4))) float f32x4;
typedef __attribute__((ext_vector_type(2))) unsigned int u32x2;

__device__ inline unsigned short f2bf(float f){
  unsigned u = __float_as_uint(f);
  u += 0x7FFFu + ((u >> 16) & 1u);   // RNE
  return (unsigned short)(u >> 16);
}
__device__ inline float sigm_(float x){ return __fdividef(1.f, 1.f + __expf(-x)); }
__device__ inline float tanh_(float x){
  float e = __expf(2.f * fminf(fmaxf(x, -15.f), 15.f));
  return __fdividef(e - 1.f, e + 1.f);
}
__device__ inline short8 ntload8(const unsigned short* p){
  return __builtin_nontemporal_load((const short8*)p);
}
__device__ inline f32x4 ntload4f(const float* p){
  return __builtin_nontemporal_load((const f32x4*)p);
}

// ---------------------------------------------------------------------------
// init: pack weights into MFMA-fragment order (see R4 comment); biasc[h*4+q].
// grid 1536 x 256.
// ---------------------------------------------------------------------------
__global__ __launch_bounds__(256) void init_kernel(
    const float* __restrict__ W_ih, const float* __restrict__ b_ih,
    const float* __restrict__ W_hh, const float* __restrict__ b_hh,
    unsigned short* __restrict__ Wf, float* __restrict__ biasc){
  const int idx = blockIdx.x*256 + threadIdx.x;
  const int e    = idx & 7;
  const int lane = (idx >> 3) & 63;
  const int frag = idx >> 9;          // 0..767
  const int q    = frag & 3;
  const int fk   = frag >> 2;         // 0..191
  const int kk   = fk % 12;
  const int w    = fk / 12;
  const int h    = w*16 + (lane & 15);
  const int k    = kk*32 + (lane >> 4)*8 + e;
  const int g    = q*H_ + h;
  float v = (k < E_) ? W_ih[g*E_ + k] : W_hh[g*H_ + (k - E_)];
  Wf[idx] = f2bf(v);
  if (idx < 4*H_){
    int hh = idx >> 2, qq = idx & 3, gg = qq*H_ + hh;
    biasc[idx] = b_ih[gg] + b_hh[gg];
  }
}

// ---------------------------------------------------------------------------
// encT[t][b][e] = bf16(tanh(x @ W_enc^T + b_enc)), MFMA 16x16x32 bf16.
// block tile 128(M over bt) x 128(N=E), BK=64, 4 waves each 32x128. grid 2048.
// ---------------------------------------------------------------------------
__global__ __launch_bounds__(256) void enc_kernel(
    const float* __restrict__ x, const float* __restrict__ W_enc,
    const float* __restrict__ b_enc, unsigned short* __restrict__ encT){
  __shared__ unsigned short As[128*64];
  __shared__ unsigned short Bs[128*64];
  __shared__ float bes[128];
  const int tid = threadIdx.x;
  const int lane = tid & 63, w = tid >> 6;
  const int l15 = lane & 15, lq = lane >> 4;
  const int m0 = blockIdx.x * 128;
  if (tid < 128) bes[tid] = b_enc[tid];

  f32x4 acc[16];
  #pragma unroll
  for (int i=0;i<16;i++) acc[i] = (f32x4)0.f;

  for (int kc = 0; kc < 4; ++kc){
    const int kb = kc*64;
    __syncthreads();
    #pragma unroll
    for (int i=0;i<4;i++){
      int u = i*256 + tid; int r = u>>3, s = u&7;
      const float* sp = x + (size_t)(m0+r)*D_ + kb + s*8;
      f32x4 v0 = ntload4f(sp);
      f32x4 v1 = ntload4f(sp+4);
      short8 pk;
      pk[0]=(short)f2bf(v0[0]); pk[1]=(short)f2bf(v0[1]); pk[2]=(short)f2bf(v0[2]); pk[3]=(short)f2bf(v0[3]);
      pk[4]=(short)f2bf(v1[0]); pk[5]=(short)f2bf(v1[1]); pk[6]=(short)f2bf(v1[2]); pk[7]=(short)f2bf(v1[3]);
      int off = (r*128 + s*16) ^ ((r&7)<<4);
      *(short8*)((char*)As + off) = pk;
    }
    #pragma unroll
    for (int i=0;i<4;i++){
      int u = i*256 + tid; int r = u>>3, s = u&7;
      const float* sp = W_enc + (size_t)r*D_ + kb + s*8;
      f32x4 v0 = *(const f32x4*)sp;
      f32x4 v1 = *(const f32x4*)(sp+4);
      short8 pk;
      pk[0]=(short)f2bf(v0[0]); pk[1]=(short)f2bf(v0[1]); pk[2]=(short)f2bf(v0[2]); pk[3]=(short)f2bf(v0[3]);
      pk[4]=(short)f2bf(v1[0]); pk[5]=(short)f2bf(v1[1]); pk[6]=(short)f2bf(v1[2]); pk[7]=(short)f2bf(v1[3]);
      int off = (r*128 + s*16) ^ ((r&7)<<4);
      *(short8*)((char*)Bs + off) = pk;
    }
    __syncthreads();
    #pragma unroll
    for (int kk=0;kk<2;kk++){
      short8 af[2];
      #pragma unroll
      for (int mi=0;mi<2;mi++){
        int r = 32*w + mi*16 + l15;
        int off = (r*128 + kk*64 + lq*16) ^ ((r&7)<<4);
        af[mi] = *(const short8*)((const char*)As + off);
      }
      #pragma unroll
      for (int nf=0;nf<8;nf++){
        int r = nf*16 + l15;
        int off = (r*128 + kk*64 + lq*16) ^ ((r&7)<<4);
        short8 bfr = *(const short8*)((const char*)Bs + off);
        #pragma unroll
        for (int mi=0;mi<2;mi++)
          acc[mi*8+nf] = __builtin_amdgcn_mfma_f32_16x16x32_bf16(af[mi], bfr, acc[mi*8+nf], 0,0,0);
      }
    }
  }
  #pragma unroll
  for (int mi=0;mi<2;mi++){
    #pragma unroll
    for (int nf=0;nf<8;nf++){
      int col = nf*16 + l15;
      float be = bes[col];
      #pragma unroll
      for (int j=0;j<4;j++){
        int bt = m0 + 32*w + mi*16 + lq*4 + j;
        int b = bt >> 6, tt = bt & 63;
        encT[((size_t)tt*B_ + b)*E_ + col] = f2bf(tanh_(acc[mi*8+nf][j] + be));
      }
    }
  }
}

// ---------------------------------------------------------------------------
// Persistent LSTM recurrence + fused loss reductions.
// 256 blocks x 1024 threads (16 waves). Block owns 16 batch rows all 64 steps.
// Per step: MFMA gates -> pointwise (c regs, h to LDS) -> barrier ->
// write-pass: wave w = batch row b0+w; lane covers h[lane*4..+4): coalesced
// f32x4 x-load, f32x4 nt ldt-store (full 128B lines), loss/ldim reg accum.
// ---------------------------------------------------------------------------
__global__ __launch_bounds__(1024, 4) void rec_kernel(
    const unsigned short* __restrict__ encT,
    const unsigned short* __restrict__ Wf,
    const float* __restrict__ biasc,
    const float* __restrict__ x,
    float* __restrict__ out_hn,
    float* __restrict__ out_loss,
    float* __restrict__ out_ldim,
    float* __restrict__ out_ldt){
  __shared__ unsigned short hbuf[2][16*256];   // 2 x 8 KB, row stride 512B, swizzled
  const int tid = threadIdx.x, lane = tid & 63, w = tid >> 6;
  const int l15 = lane & 15, lq = lane >> 4;
  const int b0 = blockIdx.x * 16;
  const int hcol = w*16 + l15;

  const f32x4 bias = *(const f32x4*)(biasc + hcol*4);
  const unsigned short* wfb = Wf + (size_t)w*24576 + lane*8;   // + (kk*4+q)*512
  const unsigned short* ep  = encT + ((size_t)(b0 + l15))*E_ + lq*8;  // + t*B_*E_ + kk*32
  const int rdbyte = l15*512 + lq*16;
  const int rsw    = (l15 & 7) << 4;
  // write-pass addresses (wave w <-> batch row b0+w, lane <-> h chunk)
  const int wpoff  = (w*512 + lane*8) ^ ((w&7)<<4);
  const float* xrow   = x       + ((size_t)(b0+w)*T_)*D_ + lane*4;   // + (t+1)*D_
  float*       ldtrow = out_ldt + ((size_t)(b0+w)*T_)*H_ + lane*4;   // + t*H_

  float creg[4] = {0.f,0.f,0.f,0.f};
  f32x4 ldacc = (f32x4)0.f;
  float lacc = 0.f;
  for (int i = tid; i < 16*256; i += 1024) hbuf[0][i] = 0;
  __syncthreads();

  short8 ae[4];
  #pragma unroll
  for (int kk=0;kk<4;kk++) ae[kk] = ntload8(ep + kk*32);

  for (int t=0; t<T_; ++t){
    char* rb = (char*)hbuf[t & 1];
    char* wb = (char*)hbuf[(t+1) & 1];

    // prefetch x row chunk for this step's write-pass (hidden under MFMA)
    f32x4 xw = (f32x4)0.f;
    if (t < T_-1) xw = ntload4f(xrow + (size_t)(t+1)*D_);
    // prefetch next step's enc frags
    short8 aen[4];
    if (t < T_-1){
      #pragma unroll
      for (int kk=0;kk<4;kk++)
        aen[kk] = ntload8(ep + (size_t)(t+1)*B_*E_ + kk*32);
    }

    f32x4 acc[4];
    #pragma unroll
    for (int q=0;q<4;q++) acc[q] = (f32x4)0.f;

    #pragma unroll
    for (int kk=0;kk<12;kk++){
      short8 af;
      if (kk < 4) af = ae[kk];
      else        af = *(const short8*)(rb + ((rdbyte + (kk-4)*64) ^ rsw));
      #pragma unroll
      for (int q=0;q<4;q++){
        short8 bq = *(const short8*)(wfb + (kk*4+q)*512);
        acc[q] = __builtin_amdgcn_mfma_f32_16x16x32_bf16(af, bq, acc[q], 0,0,0);
      }
    }

    // pointwise update; lane owns (h=hcol, batch rows b0+lq*4+j)
    #pragma unroll
    for (int j=0;j<4;j++){
      float gi = sigm_(acc[0][j] + bias[0]);
      float gf = sigm_(acc[1][j] + bias[1]);
      float gg = tanh_(acc[2][j] + bias[2]);
      float go = sigm_(acc[3][j] + bias[3]);
      float cn = gf*creg[j] + gi*gg;
      creg[j] = cn;
      float hn = go * tanh_(cn);
      int row = lq*4 + j;
      *(unsigned short*)(wb + ((row*512 + hcol*2) ^ ((row&7)<<4))) = f2bf(hn);
      if (t == T_-1)
        __builtin_nontemporal_store(hn, out_hn + (size_t)(b0+row)*H_ + hcol);
    }
    __syncthreads();

    // write-pass: full-line coalesced ldt store + fused reductions
    if (t < T_-1){
      u32x2 hv = *(const u32x2*)(wb + wpoff);
      f32x4 hf;
      hf[0] = __uint_as_float((hv[0] & 0xFFFFu) << 16);
      hf[1] = __uint_as_float(hv[0] & 0xFFFF0000u);
      hf[2] = __uint_as_float((hv[1] & 0xFFFFu) << 16);
      hf[3] = __uint_as_float(hv[1] & 0xFFFF0000u);
      f32x4 d;
      d[0] = fabsf(hf[0] - xw[0]);
      d[1] = fabsf(hf[1] - xw[1]);
      d[2] = fabsf(hf[2] - xw[2]);
      d[3] = fabsf(hf[3] - xw[3]);
      __builtin_nontemporal_store(d, (f32x4*)(ldtrow + (size_t)t*H_));
      ldacc += d;
      float s = d[0]*d[0] + d[1]*d[1] + d[2]*d[2] + d[3]*d[3];
      #pragma unroll
      for (int off=32; off; off>>=1) s += __shfl_xor(s, off);
      lacc += sqrtf(s);
    } else {
      __builtin_nontemporal_store((f32x4)0.f, (f32x4*)(ldtrow + (size_t)t*H_));
    }

    #pragma unroll
    for (int kk=0;kk<4;kk++) ae[kk] = aen[kk];
  }

  // epilogue: loss_dim and loss
  const float inv = 1.f/(float)(T_-1);
  f32x4 o = ldacc * inv;
  *(f32x4*)(out_ldim + (size_t)(b0+w)*H_ + lane*4) = o;
  if (lane == 0) out_loss[b0+w] = lacc * inv;
}

// ---------------------------------------------------------------------------
extern "C" void kernel_launch(void* const* d_in, const int* in_sizes, int n_in,
                              void* d_out, int out_size, void* d_ws, size_t ws_size,
                              hipStream_t stream){
  const float* x     = (const float*)d_in[0];
  const float* W_enc = (const float*)d_in[1];
  const float* b_enc = (const float*)d_in[2];
  const float* W_ih  = (const float*)d_in[3];
  const float* b_ih  = (const float*)d_in[4];
  const float* W_hh  = (const float*)d_in[5];
  const float* b_hh  = (const float*)d_in[6];

  // workspace: encT 64 MB | Wf 768 KB | biasc 4 KB
  char* ws = (char*)d_ws;
  unsigned short* encT  = (unsigned short*)(ws);                 // 67,108,864 B
  unsigned short* Wf    = (unsigned short*)(ws + 67108864);      //    786,432 B
  float*          biasc = (float*)        (ws + 67895296);       //      4,096 B

  float* out_hn   = (float*)d_out;
  float* out_loss = out_hn  + (size_t)B_*H_;
  float* out_ldim = out_loss + B_;
  float* out_ldt  = out_ldim + (size_t)B_*H_;

  init_kernel<<<1536, 256, 0, stream>>>(W_ih, b_ih, W_hh, b_hh, Wf, biasc);
  enc_kernel<<<2048, 256, 0, stream>>>(x, W_enc, b_enc, encT);
  rec_kernel<<<256, 1024, 0, stream>>>(encT, Wf, biasc, x, out_hn,
                                       out_loss, out_ldim, out_ldt);
}

// Round 6
// 1589.840 us; speedup vs baseline: 1.0858x; 1.0858x over previous
//
#include <hip/hip_runtime.h>

// Problem constants
#define B_  4096
#define T_  64
#define D_  256
#define E_  128
#define H_  256

typedef __attribute__((ext_vector_type(8))) short short8;
typedef __attribute__((ext_vector_type(4))) float f32x4;
typedef __attribute__((ext_vector_type(2))) unsigned int u32x2;

__device__ inline unsigned short f2bf(float f){
  unsigned u = __float_as_uint(f);
  u += 0x7FFFu + ((u >> 16) & 1u);   // RNE
  return (unsigned short)(u >> 16);
}
__device__ inline float sigm_(float x){ return __fdividef(1.f, 1.f + __expf(-x)); }
__device__ inline float tanh_(float x){
  float e = __expf(2.f * fminf(fmaxf(x, -15.f), 15.f));
  return __fdividef(e - 1.f, e + 1.f);
}
__device__ inline short8 ntload8(const unsigned short* p){
  return __builtin_nontemporal_load((const short8*)p);
}
__device__ inline f32x4 ntload4f(const float* p){
  return __builtin_nontemporal_load((const f32x4*)p);
}

// ---------------------------------------------------------------------------
// init: pack weights into per-wave MFMA fragment slices.
// frag = w*96 + fw, fw = (kk*2+hb)*4 + q  (kk in [0,12), hb in {0,1}, q in [0,4))
// element: Wf[frag*512 + lane*8 + e] =
//   W'[(w*32 + hb*16 + (lane&15))*4 + q][kk*32 + (lane>>4)*8 + e]
//   W'[h*4+q][k] = k<128 ? W_ih[q*256+h][k] : W_hh[q*256+h][k-128]
// biasc[h*4+q] = b_ih[q*256+h] + b_hh[q*256+h].  grid 1536 x 256.
// ---------------------------------------------------------------------------
__global__ __launch_bounds__(256) void init_kernel(
    const float* __restrict__ W_ih, const float* __restrict__ b_ih,
    const float* __restrict__ W_hh, const float* __restrict__ b_hh,
    unsigned short* __restrict__ Wf, float* __restrict__ biasc){
  const int idx  = blockIdx.x*256 + threadIdx.x;
  const int e    = idx & 7;
  const int lane = (idx >> 3) & 63;
  const int frag = idx >> 9;          // 0..767
  const int w    = frag / 96;
  const int fw   = frag % 96;
  const int kk   = fw >> 3;
  const int hb   = (fw >> 2) & 1;
  const int q    = fw & 3;
  const int h    = w*32 + hb*16 + (lane & 15);
  const int k    = kk*32 + (lane >> 4)*8 + e;
  const int g    = q*H_ + h;
  float v = (k < E_) ? W_ih[g*E_ + k] : W_hh[g*H_ + (k - E_)];
  Wf[idx] = f2bf(v);
  if (idx < 4*H_){
    int hh = idx >> 2, qq = idx & 3, gg = qq*H_ + hh;
    biasc[idx] = b_ih[gg] + b_hh[gg];
  }
}

// ---------------------------------------------------------------------------
// encT[t][b][e] = bf16(tanh(x @ W_enc^T + b_enc)), MFMA 16x16x32 bf16.
// ---------------------------------------------------------------------------
__global__ __launch_bounds__(256) void enc_kernel(
    const float* __restrict__ x, const float* __restrict__ W_enc,
    const float* __restrict__ b_enc, unsigned short* __restrict__ encT){
  __shared__ unsigned short As[128*64];
  __shared__ unsigned short Bs[128*64];
  __shared__ float bes[128];
  const int tid = threadIdx.x;
  const int lane = tid & 63, w = tid >> 6;
  const int l15 = lane & 15, lq = lane >> 4;
  const int m0 = blockIdx.x * 128;
  if (tid < 128) bes[tid] = b_enc[tid];

  f32x4 acc[16];
  #pragma unroll
  for (int i=0;i<16;i++) acc[i] = (f32x4)0.f;

  for (int kc = 0; kc < 4; ++kc){
    const int kb = kc*64;
    __syncthreads();
    #pragma unroll
    for (int i=0;i<4;i++){
      int u = i*256 + tid; int r = u>>3, s = u&7;
      const float* sp = x + (size_t)(m0+r)*D_ + kb + s*8;
      f32x4 v0 = ntload4f(sp);
      f32x4 v1 = ntload4f(sp+4);
      short8 pk;
      pk[0]=(short)f2bf(v0[0]); pk[1]=(short)f2bf(v0[1]); pk[2]=(short)f2bf(v0[2]); pk[3]=(short)f2bf(v0[3]);
      pk[4]=(short)f2bf(v1[0]); pk[5]=(short)f2bf(v1[1]); pk[6]=(short)f2bf(v1[2]); pk[7]=(short)f2bf(v1[3]);
      int off = (r*128 + s*16) ^ ((r&7)<<4);
      *(short8*)((char*)As + off) = pk;
    }
    #pragma unroll
    for (int i=0;i<4;i++){
      int u = i*256 + tid; int r = u>>3, s = u&7;
      const float* sp = W_enc + (size_t)r*D_ + kb + s*8;
      f32x4 v0 = *(const f32x4*)sp;
      f32x4 v1 = *(const f32x4*)(sp+4);
      short8 pk;
      pk[0]=(short)f2bf(v0[0]); pk[1]=(short)f2bf(v0[1]); pk[2]=(short)f2bf(v0[2]); pk[3]=(short)f2bf(v0[3]);
      pk[4]=(short)f2bf(v1[0]); pk[5]=(short)f2bf(v1[1]); pk[6]=(short)f2bf(v1[2]); pk[7]=(short)f2bf(v1[3]);
      int off = (r*128 + s*16) ^ ((r&7)<<4);
      *(short8*)((char*)Bs + off) = pk;
    }
    __syncthreads();
    #pragma unroll
    for (int kk=0;kk<2;kk++){
      short8 af[2];
      #pragma unroll
      for (int mi=0;mi<2;mi++){
        int r = 32*w + mi*16 + l15;
        int off = (r*128 + kk*64 + lq*16) ^ ((r&7)<<4);
        af[mi] = *(const short8*)((const char*)As + off);
      }
      #pragma unroll
      for (int nf=0;nf<8;nf++){
        int r = nf*16 + l15;
        int off = (r*128 + kk*64 + lq*16) ^ ((r&7)<<4);
        short8 bfr = *(const short8*)((const char*)Bs + off);
        #pragma unroll
        for (int mi=0;mi<2;mi++)
          acc[mi*8+nf] = __builtin_amdgcn_mfma_f32_16x16x32_bf16(af[mi], bfr, acc[mi*8+nf], 0,0,0);
      }
    }
  }
  #pragma unroll
  for (int mi=0;mi<2;mi++){
    #pragma unroll
    for (int nf=0;nf<8;nf++){
      int col = nf*16 + l15;
      float be = bes[col];
      #pragma unroll
      for (int j=0;j<4;j++){
        int bt = m0 + 32*w + mi*16 + lq*4 + j;
        int b = bt >> 6, tt = bt & 63;
        encT[((size_t)tt*B_ + b)*E_ + col] = f2bf(tanh_(acc[mi*8+nf][j] + be));
      }
    }
  }
}

// ---------------------------------------------------------------------------
// Weights-stationary persistent LSTM recurrence + fused loss reductions.
// 256 blocks x 512 threads (8 waves, 2/SIMD, 256-VGPR budget).
// Wave w owns h in [w*32, w*32+32) x 4 gates = 96 weight frags:
//   frags 0-23 (kk 0-2)  -> persistent VGPRs (96 regs)
//   frags 24-39 (kk 3-4) -> LDS (16 KB/wave, 128 KB total, loaded once)
//   frags 40-95 (kk 5-11)-> streamed per step (56 KB/wave), 3-deep pipeline
// h in LDS dbuf (16 KB); c + loss accumulators in regs; 1 barrier/step.
// ---------------------------------------------------------------------------
__global__ __launch_bounds__(512, 2) void rec_kernel(
    const unsigned short* __restrict__ encT,
    const unsigned short* __restrict__ Wf,
    const float* __restrict__ biasc,
    const float* __restrict__ x,
    float* __restrict__ out_hn,
    float* __restrict__ out_loss,
    float* __restrict__ out_ldim,
    float* __restrict__ out_ldt){
  extern __shared__ char smem[];          // 147456 B total
  char* hbs  = smem;                      // hbuf[2][16 rows][256 h] bf16, 16 KB
  char* wlds = smem + 16384;              // [8 waves][16 frags][1024 B] = 128 KB
  const int tid = threadIdx.x, lane = tid & 63, w = tid >> 6;
  const int l15 = lane & 15, lq = lane >> 4;
  const int b0 = blockIdx.x * 16;

  const f32x4 bias0 = *(const f32x4*)(biasc + (w*32 + l15)*4);
  const f32x4 bias1 = *(const f32x4*)(biasc + (w*32 + 16 + l15)*4);

  // weight tiers
  const unsigned short* wsl = Wf + (size_t)w*96*512 + lane*8;
  short8 wreg[24];
  #pragma unroll
  for (int l=0;l<24;l++) wreg[l] = *(const short8*)(wsl + l*512);
  #pragma unroll
  for (int l=0;l<16;l++){
    short8 v = *(const short8*)(wsl + (24+l)*512);
    *(short8*)(wlds + ((w*16+l)<<10) + lane*16) = v;
  }
  const unsigned short* wstr = wsl + 40*512;   // streamed frags (stream idx *512)

  *(short8*)(hbs + tid*16) = (short8)(short)0;   // zero hbuf[0] (8 KB)
  __syncthreads();

  const unsigned short* ep = encT + (size_t)(b0 + l15)*E_ + lq*8;
  const int rdb = l15*512 + lq*16;
  const int rsw = (l15 & 7) << 4;
  // write-pass: wave w handles batch rows w and w+8
  const int row1 = w + 8;
  const float* xr0 = x + (size_t)(b0+w)*T_*D_ + lane*4;
  const float* xr1 = x + (size_t)(b0+row1)*T_*D_ + lane*4;
  float* lt0 = out_ldt + (size_t)(b0+w)*T_*H_ + lane*4;
  float* lt1 = out_ldt + (size_t)(b0+row1)*T_*H_ + lane*4;
  const int wp0 = (w*512 + lane*8) ^ ((w&7)<<4);
  const int wp1 = (row1*512 + lane*8) ^ ((row1&7)<<4);

  float creg[8];
  #pragma unroll
  for (int i=0;i<8;i++) creg[i] = 0.f;
  f32x4 ld0 = (f32x4)0.f, ld1 = (f32x4)0.f;
  float la0 = 0.f, la1 = 0.f;

  for (int t=0; t<T_; ++t){
    char* rb = hbs + (t&1)*8192;
    char* wb = hbs + ((t+1)&1)*8192;

    // stream pipeline prologue: halves 0-2 in flight
    short8 sb[3][4];
    #pragma unroll
    for (int i=0;i<3;i++)
      #pragma unroll
      for (int q=0;q<4;q++)
        sb[i][q] = *(const short8*)(wstr + (i*4+q)*512);

    // enc A-frags (kk 0-3)
    short8 ae[4];
    #pragma unroll
    for (int kk=0;kk<4;kk++) ae[kk] = ntload8(ep + (size_t)t*B_*E_ + kk*32);

    f32x4 acc[8];
    #pragma unroll
    for (int i=0;i<8;i++) acc[i] = (f32x4)0.f;

    // stream tier: kk 5..11, A from hbuf; 14 half-batches, 3-deep rolling
    short8 ah;
    #pragma unroll
    for (int i=0;i<14;i++){
      const int kk = 5 + (i>>1), hb = i & 1;
      if ((i & 1) == 0)
        ah = *(const short8*)(rb + ((rdb + (kk-4)*64) ^ rsw));
      #pragma unroll
      for (int q=0;q<4;q++)
        acc[hb*4+q] = __builtin_amdgcn_mfma_f32_16x16x32_bf16(ah, sb[i%3][q], acc[hb*4+q], 0,0,0);
      if (i+3 < 14){
        #pragma unroll
        for (int q=0;q<4;q++)
          sb[i%3][q] = *(const short8*)(wstr + ((i+3)*4+q)*512);
      }
    }
    // register tier: kk 0..2 (A = enc)
    #pragma unroll
    for (int kk=0;kk<3;kk++)
      #pragma unroll
      for (int hb=0;hb<2;hb++)
        #pragma unroll
        for (int q=0;q<4;q++)
          acc[hb*4+q] = __builtin_amdgcn_mfma_f32_16x16x32_bf16(ae[kk], wreg[kk*8+hb*4+q], acc[hb*4+q], 0,0,0);
    // LDS tier: kk 3 (A = ae[3]), kk 4 (A = hbuf chunk 0)
    #pragma unroll
    for (int hb=0;hb<2;hb++)
      #pragma unroll
      for (int q=0;q<4;q++){
        short8 wl = *(const short8*)(wlds + ((w*16 + hb*4 + q)<<10) + lane*16);
        acc[hb*4+q] = __builtin_amdgcn_mfma_f32_16x16x32_bf16(ae[3], wl, acc[hb*4+q], 0,0,0);
      }
    {
      short8 ah4 = *(const short8*)(rb + (rdb ^ rsw));
      #pragma unroll
      for (int hb=0;hb<2;hb++)
        #pragma unroll
        for (int q=0;q<4;q++){
          short8 wl = *(const short8*)(wlds + ((w*16 + 8 + hb*4 + q)<<10) + lane*16);
          acc[hb*4+q] = __builtin_amdgcn_mfma_f32_16x16x32_bf16(ah4, wl, acc[hb*4+q], 0,0,0);
        }
    }

    // pointwise update: 8 cells/lane (hb x j)
    #pragma unroll
    for (int hb=0;hb<2;hb++){
      const f32x4 bb = hb ? bias1 : bias0;
      const int h = w*32 + hb*16 + l15;
      #pragma unroll
      for (int j=0;j<4;j++){
        float gi = sigm_(acc[hb*4+0][j] + bb[0]);
        float gf = sigm_(acc[hb*4+1][j] + bb[1]);
        float gg = tanh_(acc[hb*4+2][j] + bb[2]);
        float go = sigm_(acc[hb*4+3][j] + bb[3]);
        float cn = gf*creg[hb*4+j] + gi*gg;
        creg[hb*4+j] = cn;
        float hn = go * tanh_(cn);
        const int row = lq*4 + j;
        *(unsigned short*)(wb + ((row*512 + h*2) ^ ((row&7)<<4))) = f2bf(hn);
        if (t == T_-1)
          __builtin_nontemporal_store(hn, out_hn + (size_t)(b0+row)*H_ + h);
      }
    }
    __syncthreads();

    // write-pass: full-line coalesced ldt stores + fused reductions
    if (t < T_-1){
      f32x4 xw0 = ntload4f(xr0 + (size_t)(t+1)*D_);
      f32x4 xw1 = ntload4f(xr1 + (size_t)(t+1)*D_);
      u32x2 hv0 = *(const u32x2*)(wb + wp0);
      u32x2 hv1 = *(const u32x2*)(wb + wp1);
      f32x4 d0, d1;
      d0[0] = fabsf(__uint_as_float((hv0[0] & 0xFFFFu) << 16) - xw0[0]);
      d0[1] = fabsf(__uint_as_float(hv0[0] & 0xFFFF0000u)     - xw0[1]);
      d0[2] = fabsf(__uint_as_float((hv0[1] & 0xFFFFu) << 16) - xw0[2]);
      d0[3] = fabsf(__uint_as_float(hv0[1] & 0xFFFF0000u)     - xw0[3]);
      d1[0] = fabsf(__uint_as_float((hv1[0] & 0xFFFFu) << 16) - xw1[0]);
      d1[1] = fabsf(__uint_as_float(hv1[0] & 0xFFFF0000u)     - xw1[1]);
      d1[2] = fabsf(__uint_as_float((hv1[1] & 0xFFFFu) << 16) - xw1[2]);
      d1[3] = fabsf(__uint_as_float(hv1[1] & 0xFFFF0000u)     - xw1[3]);
      __builtin_nontemporal_store(d0, (f32x4*)(lt0 + (size_t)t*H_));
      __builtin_nontemporal_store(d1, (f32x4*)(lt1 + (size_t)t*H_));
      ld0 += d0; ld1 += d1;
      float s0 = d0[0]*d0[0] + d0[1]*d0[1] + d0[2]*d0[2] + d0[3]*d0[3];
      float s1 = d1[0]*d1[0] + d1[1]*d1[1] + d1[2]*d1[2] + d1[3]*d1[3];
      #pragma unroll
      for (int off=32; off; off>>=1){ s0 += __shfl_xor(s0, off); s1 += __shfl_xor(s1, off); }
      la0 += sqrtf(s0); la1 += sqrtf(s1);
    } else {
      __builtin_nontemporal_store((f32x4)0.f, (f32x4*)(lt0 + (size_t)t*H_));
      __builtin_nontemporal_store((f32x4)0.f, (f32x4*)(lt1 + (size_t)t*H_));
    }
  }

  // epilogue: loss_dim and loss for rows b0+w, b0+w+8
  const float inv = 1.f/(float)(T_-1);
  *(f32x4*)(out_ldim + (size_t)(b0+w)*H_    + lane*4) = ld0*inv;
  *(f32x4*)(out_ldim + (size_t)(b0+row1)*H_ + lane*4) = ld1*inv;
  if (lane == 0){
    out_loss[b0+w]    = la0*inv;
    out_loss[b0+row1] = la1*inv;
  }
}

// ---------------------------------------------------------------------------
extern "C" void kernel_launch(void* const* d_in, const int* in_sizes, int n_in,
                              void* d_out, int out_size, void* d_ws, size_t ws_size,
                              hipStream_t stream){
  const float* x     = (const float*)d_in[0];
  const float* W_enc = (const float*)d_in[1];
  const float* b_enc = (const float*)d_in[2];
  const float* W_ih  = (const float*)d_in[3];
  const float* b_ih  = (const float*)d_in[4];
  const float* W_hh  = (const float*)d_in[5];
  const float* b_hh  = (const float*)d_in[6];

  // workspace: encT 64 MB | Wf 768 KB | biasc 4 KB
  char* ws = (char*)d_ws;
  unsigned short* encT  = (unsigned short*)(ws);                 // 67,108,864 B
  unsigned short* Wf    = (unsigned short*)(ws + 67108864);      //    786,432 B
  float*          biasc = (float*)        (ws + 67895296);       //      4,096 B

  float* out_hn   = (float*)d_out;
  float* out_loss = out_hn  + (size_t)B_*H_;
  float* out_ldim = out_loss + B_;
  float* out_ldt  = out_ldim + (size_t)B_*H_;

  (void)hipFuncSetAttribute((const void*)rec_kernel,
      hipFuncAttributeMaxDynamicSharedMemorySize, 147456);

  init_kernel<<<1536, 256, 0, stream>>>(W_ih, b_ih, W_hh, b_hh, Wf, biasc);
  enc_kernel<<<2048, 256, 0, stream>>>(x, W_enc, b_enc, encT);
  rec_kernel<<<256, 512, 147456, stream>>>(encT, Wf, biasc, x, out_hn,
                                           out_loss, out_ldim, out_ldt);
}